// Round 7
// baseline (1864.244 us; speedup 1.0000x reference)
//
#include <hip/hip_runtime.h>

#define NBATCH 8192
#define NFEAT  3072                      // 48*64
#define TOT    ((size_t)NBATCH * NFEAT)  // 25,165,824 elems
#define ZBYTES (TOT * 2)                 // bf16 chain slot
#define YBYTES (TOT)                     // u8 residual slot
#define GRID   512                       // 16 elements/block = 2 batches of 8

typedef unsigned short u16;
typedef unsigned int   u32;
typedef unsigned char  u8;

typedef __attribute__((ext_vector_type(8))) short bf16x8;  // MFMA A/B frag
typedef __attribute__((ext_vector_type(4))) float f32x4;   // MFMA C/D frag

__device__ __forceinline__ float sigm(float u) {
  return 1.0f / (1.0f + __expf(-u));
}
__device__ __forceinline__ u16 f2b(float f) {           // fp32 -> bf16 RNE
  const u32 u = __float_as_uint(f);
  return (u16)((u + 0x7FFFu + ((u >> 16) & 1u)) >> 16);
}
__device__ __forceinline__ float b2f(u16 h) {
  return __uint_as_float(((u32)h) << 16);
}
__device__ __forceinline__ u32 pack2(float a, float b) {
  return (u32)f2b(a) | ((u32)f2b(b) << 16);
}

// One GraphConvolution layer, MFMA core, 8-element batched schedule:
//   transform 8 elems -> barrier A -> issue next batch loads -> mm 8 elems
//   -> barrier B.  2 barriers per 8 elements (was 1/element): amortizes the
//   compiler's vmcnt(0)-drain-before-s_barrier, and keeps 24 loads in flight.
// mm1: S^T = (H @ W)^T (A from swizzled LDS, B=W regs); mm2: Z^T = S^T @ att^T
// (A from wave-private STB rows, B=att^T regs) -> no intra-mm barrier.
// MODE 0: h = x (fp32); MODE 1: h = sigm(bn0(in0)), capture u8 y; MODE 2:
// h = sigm(bn0(in0)) + yres_in/255.
// zout may alias in0v (in-place chain): element b touched only by block
// b%GRID; its load (prefetch, prev batch) precedes its store (own batch).
template <int MODE>
__global__ __launch_bounds__(256, 2)
void gcn_layer(const void* in0v,
               const u8*  yres_in,
               u8*        yres_out,
               u16*       zout,
               const float* __restrict__ Wg,     // 64x64 [k][g]
               const float* __restrict__ Ag,     // 48x48 [n][m]
               const float* __restrict__ biasg,  // 64
               const float* __restrict__ gam0,
               const float* __restrict__ bet0,
               const float* __restrict__ sum0,
               const float* __restrict__ sq0,
               float* __restrict__ osum,
               float* __restrict__ osq)
{
  // Hl: [8 elems][48 rows][64 bf16 = 128 B], XOR-swizzle byte ^= (row&7)<<4
  // STB: S^T [64 g-rows][64 m bf16], same swizzle; m=48..63 zeroed once
  __shared__ __align__(16) char HlB[8][6144];   // 48 KB
  __shared__ __align__(16) char STB[8192];      //  8 KB  (56 KB -> 2 blocks/CU)

  const int t    = threadIdx.x;
  const int lane = t & 63;
  const int wv   = t >> 6;       // wave id == g-tile (0..3)
  const int lr   = lane & 15;
  const int lk   = lane >> 4;

  // ---- one-time W / att fragments (bf16, registers) ----
  // A/B frag map (mfma_f32_16x16x32_bf16): A[row][k] row=lane&15,
  // k=8*(lane>>4)+j; B[k][col] col=lane&15, same k. C/D: col=lane&15,
  // row=4*(lane>>4)+i  [learn_hip m89/m91].
  bf16x8 Wf[2];                 // mm1 B-op: W[k][g], g-tile wv
  #pragma unroll
  for (int ks = 0; ks < 2; ++ks)
    #pragma unroll
    for (int j = 0; j < 8; ++j) {
      const int k = ks * 32 + lk * 8 + j;
      Wf[ks][j] = (short)f2b(Wg[k * 64 + wv * 16 + lr]);
    }
  bf16x8 Af[3][2];              // mm2 B-op: att^T[m][n], n-tile nt
  #pragma unroll
  for (int nt = 0; nt < 3; ++nt)
    #pragma unroll
    for (int ks = 0; ks < 2; ++ks)
      #pragma unroll
      for (int j = 0; j < 8; ++j) {
        const int m = ks * 32 + lk * 8 + j;
        Af[nt][ks][j] = (m < 48) ? (short)f2b(Ag[(nt * 16 + lr) * 48 + m])
                                 : (short)0;
      }
  const float4 bi = *(const float4*)(biasg + wv * 16 + lk * 4);

  // ---- zero STB pad region (m=48..63) once; first barrier covers it ----
  {
    const int row = t >> 2, ch = t & 3;
    const int off = (96 + ch * 8) ^ ((row & 7) << 4);
    *(uint2*)(STB + row * 128 + off) = make_uint2(0u, 0u);
  }

  // ---- BN constants for this thread's fixed load coords ----
  const float invB = 1.0f / 8192.0f;
  float sc0[12], sh0[12];
  if (MODE >= 1) {
    #pragma unroll
    for (int q = 0; q < 3; ++q) {
      const int j = (t + 256 * q) * 4;
      #pragma unroll
      for (int c = 0; c < 4; ++c) {
        const float mu = sum0[j + c] * invB;
        const float va = fmaf(-mu, mu, sq0[j + c] * invB);
        const float s  = gam0[j + c] * rsqrtf(va + 1e-5f);
        sc0[q * 4 + c] = s;
        sh0[q * 4 + c] = fmaf(-mu, s, bet0[j + c]);
      }
    }
  }

  float ssum[12], ssq[12];
  #pragma unroll
  for (int i = 0; i < 12; ++i) { ssum[i] = 0.f; ssq[i] = 0.f; }

  // ---- register staging for one 8-element batch ----
  float4  fst[8][3];   // MODE 0
  ushort4 vst[8][3];   // MODE 1/2
  uchar4  yst[8][3];   // MODE 2
  uchar4  yq [8][3];   // MODE 1 deferred y-stores

  auto issue = [&](int s) {
    #pragma unroll
    for (int e = 0; e < 8; ++e) {
      const int b = blockIdx.x + (s * 8 + e) * GRID;
      if (MODE == 0) {
        const float4* p = (const float4*)((const float*)in0v + (size_t)b * NFEAT);
        #pragma unroll
        for (int q = 0; q < 3; ++q) fst[e][q] = p[t + 256 * q];
      } else {
        const ushort4* p = (const ushort4*)((const u16*)in0v + (size_t)b * NFEAT);
        #pragma unroll
        for (int q = 0; q < 3; ++q) vst[e][q] = p[t + 256 * q];
        if (MODE == 2) {
          const uchar4* py = (const uchar4*)(yres_in + (size_t)b * NFEAT);
          #pragma unroll
          for (int q = 0; q < 3; ++q) yst[e][q] = py[t + 256 * q];
        }
      }
    }
  };

  issue(0);

  for (int s = 0; s < 2; ++s) {
    // ---- transform batch s -> HlB[e] (bf16, swizzled) ----
    #pragma unroll
    for (int e = 0; e < 8; ++e) {
      #pragma unroll
      for (int q = 0; q < 3; ++q) {
        float4 v;
        if (MODE == 0) {
          v = fst[e][q];
        } else {
          v = make_float4(b2f(vst[e][q].x), b2f(vst[e][q].y),
                          b2f(vst[e][q].z), b2f(vst[e][q].w));
          v.x = sigm(fmaf(v.x, sc0[q * 4 + 0], sh0[q * 4 + 0]));
          v.y = sigm(fmaf(v.y, sc0[q * 4 + 1], sh0[q * 4 + 1]));
          v.z = sigm(fmaf(v.z, sc0[q * 4 + 2], sh0[q * 4 + 2]));
          v.w = sigm(fmaf(v.w, sc0[q * 4 + 3], sh0[q * 4 + 3]));
          if (MODE == 1) {   // defer the u8 store to after barrier A
            yq[e][q].x = (u8)fmaf(v.x, 255.f, 0.5f);
            yq[e][q].y = (u8)fmaf(v.y, 255.f, 0.5f);
            yq[e][q].z = (u8)fmaf(v.z, 255.f, 0.5f);
            yq[e][q].w = (u8)fmaf(v.w, 255.f, 0.5f);
          }
          if (MODE == 2) {
            v.x += (float)yst[e][q].x * (1.f / 255.f);
            v.y += (float)yst[e][q].y * (1.f / 255.f);
            v.z += (float)yst[e][q].z * (1.f / 255.f);
            v.w += (float)yst[e][q].w * (1.f / 255.f);
          }
        }
        const int j   = (t + 256 * q) * 4;
        const int row = j >> 6;
        const int cb  = (j & 63) * 2;
        *(uint2*)(HlB[e] + row * 128 + (cb ^ ((row & 7) << 4))) =
            make_uint2(pack2(v.x, v.y), pack2(v.z, v.w));
      }
    }

    __syncthreads();   // (A) Hl batch ready; no fresh vmem pending here

    if (s == 0) issue(1);   // 24 loads in flight across the whole mm phase

    if (MODE == 1) {        // y-stores drain at barrier B (hidden under mm)
      #pragma unroll
      for (int e = 0; e < 8; ++e) {
        const int b = blockIdx.x + (s * 8 + e) * GRID;
        #pragma unroll
        for (int q = 0; q < 3; ++q)
          *(uchar4*)(yres_out + (size_t)b * NFEAT + (size_t)(t + 256 * q) * 4)
              = yq[e][q];
      }
    }

    // ---- mm phase: 8 elements, no barriers (STB rows are wave-private;
    //      in-wave LDS ordering covers WAR across elements) ----
    #pragma unroll
    for (int e = 0; e < 8; ++e) {
      const int b = blockIdx.x + (s * 8 + e) * GRID;

      // mm1: S^T tiles for this wave's g-columns -> STB
      #pragma unroll
      for (int mt = 0; mt < 3; ++mt) {
        f32x4 acc = {0.f, 0.f, 0.f, 0.f};
        #pragma unroll
        for (int ks = 0; ks < 2; ++ks) {
          const int row = mt * 16 + lr;
          const int off = (ks * 64 + lk * 16) ^ ((row & 7) << 4);
          const bf16x8 aF = *(const bf16x8*)(HlB[e] + row * 128 + off);
          acc = __builtin_amdgcn_mfma_f32_16x16x32_bf16(aF, Wf[ks], acc, 0, 0, 0);
        }
        const int g   = wv * 16 + lr;
        const int off = (mt * 32 + lk * 8) ^ ((g & 7) << 4);
        *(uint2*)(STB + g * 128 + off) =
            make_uint2(pack2(acc[0], acc[1]), pack2(acc[2], acc[3]));
      }

      // mm2: Z^T = S^T @ att^T
      bf16x8 sF[2];
      {
        const int g = wv * 16 + lr;
        #pragma unroll
        for (int ks = 0; ks < 2; ++ks) {
          const int off = (ks * 64 + lk * 16) ^ ((g & 7) << 4);
          sF[ks] = *(const bf16x8*)(STB + g * 128 + off);
        }
      }
      u16* zp = zout + (size_t)b * NFEAT;
      #pragma unroll
      for (int nt = 0; nt < 3; ++nt) {
        f32x4 acc = {0.f, 0.f, 0.f, 0.f};
        acc = __builtin_amdgcn_mfma_f32_16x16x32_bf16(sF[0], Af[nt][0], acc, 0, 0, 0);
        acc = __builtin_amdgcn_mfma_f32_16x16x32_bf16(sF[1], Af[nt][1], acc, 0, 0, 0);
        const int n  = nt * 16 + lr;
        const int gb = wv * 16 + lk * 4;
        const float v0 = acc[0] + bi.x;
        const float v1 = acc[1] + bi.y;
        const float v2 = acc[2] + bi.z;
        const float v3 = acc[3] + bi.w;
        ushort4 zq4;
        zq4.x = f2b(v0); zq4.y = f2b(v1); zq4.z = f2b(v2); zq4.w = f2b(v3);
        *(ushort4*)(zp + n * 64 + gb) = zq4;
        const float vr[4] = {b2f(zq4.x), b2f(zq4.y), b2f(zq4.z), b2f(zq4.w)};
        #pragma unroll
        for (int c = 0; c < 4; ++c) {
          ssum[nt * 4 + c] += vr[c];
          ssq[nt * 4 + c]   = fmaf(vr[c], vr[c], ssq[nt * 4 + c]);
        }
      }
    }

    __syncthreads();   // (B) mm reads done; prefetch loads + stores drained
  }

  // ---- flush stats (coords unique per (lane,wave) within a block) ----
  #pragma unroll
  for (int r = 0; r < 3; ++r) {
    #pragma unroll
    for (int c = 0; c < 4; ++c) {
      const int j = (r * 16 + lr) * 64 + wv * 16 + lk * 4 + c;
      atomicAdd(&osum[j], ssum[r * 4 + c]);
      atomicAdd(&osq[j],  ssq[r * 4 + c]);
    }
  }
}

// out = sigmoid(bn10(z10)) + x   (z10 bf16 in ws chain, x/out fp32)
__global__ __launch_bounds__(256)
void gcn_final(const u16* __restrict__ z,
               const float* __restrict__ xin,
               const float* __restrict__ gam,
               const float* __restrict__ bet,
               const float* __restrict__ sum,
               const float* __restrict__ sq,
               float* __restrict__ outp)
{
  const float invB = 1.0f / 8192.0f;
  const int total4 = (int)(TOT / 4);
  const int stride = gridDim.x * blockDim.x;
  for (int i4 = blockIdx.x * blockDim.x + threadIdx.x; i4 < total4; i4 += stride) {
    const int j = (i4 % 768) * 4;
    const ushort4 zq = ((const ushort4*)z)[i4];
    const float4  xv = ((const float4*)xin)[i4];
    const float zz[4] = {b2f(zq.x), b2f(zq.y), b2f(zq.z), b2f(zq.w)};
    const float xx[4] = {xv.x, xv.y, xv.z, xv.w};
    float o[4];
    #pragma unroll
    for (int c = 0; c < 4; ++c) {
      const float mu = sum[j + c] * invB;
      const float va = fmaf(-mu, mu, sq[j + c] * invB);
      const float s  = gam[j + c] * rsqrtf(va + 1e-5f);
      const float sh = fmaf(-mu, s, bet[j + c]);
      o[c] = sigm(fmaf(zz[c], s, sh)) + xx[c];
    }
    ((float4*)outp)[i4] = make_float4(o[0], o[1], o[2], o[3]);
  }
}

extern "C" void kernel_launch(void* const* d_in, const int* in_sizes, int n_in,
                              void* d_out, int out_size, void* d_ws, size_t ws_size,
                              hipStream_t stream)
{
  const float* x    = (const float*)d_in[0];
  const float* W    = (const float*)d_in[1];
  const float* att  = (const float*)d_in[2];
  const float* bias = (const float*)d_in[3];
  const float* gam  = (const float*)d_in[4];
  const float* bet  = (const float*)d_in[5];
  float* out = (float*)d_out;

  // d_out hosts u8 residuals y1..y4 (exactly out bytes, dead before gcn_final).
  // d_ws: bf16 chain (z0->...->z10 in place) + u8 y5 + stats.
  u8* y1 = (u8*)d_out;
  u8* y2 = y1 + TOT;
  u8* y3 = y2 + TOT;
  u8* y4 = y3 + TOT;

  const size_t statbytes = (size_t)2 * 11 * NFEAT * 4;
  const size_t need = ZBYTES + YBYTES + statbytes;   // ~75.8 MB (fits, R4/R6)
  if (ws_size < need) {
    hipMemcpyAsync(out, x, TOT * 4, hipMemcpyDeviceToDevice, stream);  // absmax ~1.0 diag
    return;
  }

  char* wsb = (char*)d_ws;
  u16* chain = (u16*)wsb;
  u8*  y5    = (u8*)(wsb + ZBYTES);
  float* stats = (float*)(wsb + ZBYTES + YBYTES);
  hipMemsetAsync(stats, 0, statbytes, stream);

  auto sumP = [&](int l) { return stats + (size_t)l * NFEAT; };
  auto sqP  = [&](int l) { return stats + (size_t)(11 + l) * NFEAT; };

  const dim3 grd(GRID), blk(256);
  auto G = [&](int mode, const void* i0, const u8* yin, u8* yout, int k) {
    const int p = (k > 0) ? (k - 1) : 0;
    const float* Wk = W + (size_t)k * 4096;
    const float* Ak = att + (size_t)k * 2304;
    const float* bk = bias + (size_t)k * 64;
    const float* g0p = gam + (size_t)p * NFEAT;
    const float* b0p = bet + (size_t)p * NFEAT;
    if (mode == 0)
      gcn_layer<0><<<grd, blk, 0, stream>>>(i0, yin, yout, chain, Wk, Ak, bk,
          g0p, b0p, sumP(p), sqP(p), sumP(k), sqP(k));
    else if (mode == 1)
      gcn_layer<1><<<grd, blk, 0, stream>>>(i0, yin, yout, chain, Wk, Ak, bk,
          g0p, b0p, sumP(p), sqP(p), sumP(k), sqP(k));
    else
      gcn_layer<2><<<grd, blk, 0, stream>>>(i0, yin, yout, chain, Wk, Ak, bk,
          g0p, b0p, sumP(p), sqP(p), sumP(k), sqP(k));
  };

  G(0, x,     nullptr, y1, 0);   // z0            (yout unused)
  G(1, chain, nullptr, y1, 1);   // z1, capture y1
  G(1, chain, nullptr, y2, 2);   // z2, capture y2
  G(1, chain, nullptr, y3, 3);   // z3, capture y3
  G(1, chain, nullptr, y4, 4);   // z4, capture y4
  G(1, chain, nullptr, y5, 5);   // z5, capture y5
  G(2, chain, y5, nullptr, 6);   // h = y6 + y5 -> z6
  G(2, chain, y4, nullptr, 7);   // h = y7 + y4 -> z7
  G(2, chain, y3, nullptr, 8);   // h = y8 + y3 -> z8
  G(2, chain, y2, nullptr, 9);   // h = y9 + y2 -> z9
  G(2, chain, y1, nullptr, 10);  // h = y10 + y1 -> z10
  gcn_final<<<dim3(2048), blk, 0, stream>>>(chain, x, gam + (size_t)10 * NFEAT,
                                            bet + (size_t)10 * NFEAT,
                                            sumP(10), sqP(10), out);
}